// Round 1
// 406.608 us; speedup vs baseline: 1.0561x; 1.0561x over previous
//
#include <hip/hip_runtime.h>
#include <cmath>

#define S_   4
#define DIN  1024
#define D_   256
#define B_   4
#define T_   4096
#define BT_  (B_*T_)
#define GN   (S_*3*D_)     // 3072 concat N for the big GEMM
#define CHUNKS 128
#define CL   (T_/CHUNKS)   // 32

typedef short bf16x8 __attribute__((ext_vector_type(8)));
typedef float f32x4  __attribute__((ext_vector_type(4)));

struct SC { float are[S_]; float aim[S_]; float bsc[S_]; };

__device__ inline unsigned short f2bf(float f) {
    unsigned int u = __builtin_bit_cast(unsigned int, f);
    unsigned int r = (u + 0x7FFFu + ((u >> 16) & 1u)) >> 16;
    return (unsigned short)r;
}
__device__ inline float bf2f_lo(unsigned int u) {
    return __builtin_bit_cast(float, u << 16);
}
__device__ inline float bf2f_hi(unsigned int u) {
    return __builtin_bit_cast(float, u & 0xFFFF0000u);
}
// omg u16 fixed-point decode: (u + 0.5) / 65536
__device__ inline float u16om(unsigned int u) {
    return ((float)u + 0.5f) * (1.f/65536.f);
}

#define GLD_LDS(gp, lp) \
    __builtin_amdgcn_global_load_lds( \
        (const __attribute__((address_space(1))) void*)(gp), \
        (__attribute__((address_space(3))) void*)(lp), 16, 0, 0)

// ---------------------------------------------------------------------------
// x fp32 -> bf16
// ---------------------------------------------------------------------------
__global__ __launch_bounds__(256) void kconv_x(
    const float* __restrict__ x, unsigned short* __restrict__ xb)
{
    const size_t i = ((size_t)blockIdx.x*256 + threadIdx.x)*4;
    const float4 v = *(const float4*)(x + i);
    ushort4 o;
    o.x = f2bf(v.x); o.y = f2bf(v.y); o.z = f2bf(v.z); o.w = f2bf(v.w);
    *(ushort4*)(xb + i) = o;
}

// ---------------------------------------------------------------------------
// Weight transpose+convert (Wg2 only): src [S][K][N] fp32 -> [S][N][K] bf16
// ---------------------------------------------------------------------------
__global__ __launch_bounds__(256) void kconv_w(
    const float* __restrict__ src, unsigned short* __restrict__ dst,
    int K, int N, size_t dst_s_stride)
{
    __shared__ float t[32][33];
    const int k0 = blockIdx.x*32, n0 = blockIdx.y*32, s = blockIdx.z;
    const float* sp = src + (size_t)s*K*N;
    unsigned short* dp = dst + (size_t)s*dst_s_stride;
    const int c = threadIdx.x & 31, r0 = threadIdx.x >> 5;
    #pragma unroll
    for (int p = 0; p < 4; ++p)
        t[r0 + p*8][c] = sp[(size_t)(k0 + r0 + p*8)*N + n0 + c];
    __syncthreads();
    #pragma unroll
    for (int p = 0; p < 4; ++p)
        dp[(size_t)(n0 + r0 + p*8)*K + k0 + c] = f2bf(t[c][r0 + p*8]);
}

// ---------------------------------------------------------------------------
// Merged transpose+convert for the three DIN x D_ weights -> Bct layout.
// z = widx*S_ + s; widx 0:Wg1 1:Wdr 2:Wdi
// ---------------------------------------------------------------------------
__global__ __launch_bounds__(256) void kconv_w3(
    const float* __restrict__ Wg1, const float* __restrict__ Wdr,
    const float* __restrict__ Wdi, unsigned short* __restrict__ dst)
{
    __shared__ float t[32][33];
    const int z = blockIdx.z;
    const int widx = z >> 2, s = z & 3;
    const float* src = (widx == 0) ? Wg1 : ((widx == 1) ? Wdr : Wdi);
    const float* sp = src + (size_t)s*DIN*D_;
    unsigned short* dp = dst + (size_t)s*768*DIN + (size_t)widx*D_*DIN;
    const int k0 = blockIdx.x*32, n0 = blockIdx.y*32;
    const int c = threadIdx.x & 31, r0 = threadIdx.x >> 5;
    #pragma unroll
    for (int p = 0; p < 4; ++p)
        t[r0 + p*8][c] = sp[(size_t)(k0 + r0 + p*8)*D_ + n0 + c];
    __syncthreads();
    #pragma unroll
    for (int p = 0; p < 4; ++p)
        dp[(size_t)(n0 + r0 + p*8)*DIN + k0 + c] = f2bf(t[c][r0 + p*8]);
}

// ---------------------------------------------------------------------------
// k1_8p: C[16384][3072] = xb * Bct^T, 256x256 tile, BK=64, 8 waves (2M x 4N),
// 8-phase schedule, counted vmcnt (never 0 in steady state), st-swizzled LDS.
// LDS: 8 half-tile slots of 16 KiB: [buf][op][half] (128 rows x 64 k bf16).
// Quadrant order per K-tile: (ih,jh) = (0,0),(0,1),(1,1),(1,0).
// Issue schedule: P1:A1[t+1] P2:B0[t+1] P3:A0[t+2] P4:B1[t+2]
//                 P5:A1[t+2] P6:B0[t+2] P7:A0[t+3] P8:B1[t+3]
// Waits: vmcnt(4) at P4 and P8 (covers 4 half-tiles needed next), vmcnt(0)
// in the last iteration.
// ---------------------------------------------------------------------------
template<bool DRVB>
__global__ __launch_bounds__(512, 2) void k1_8p(
    const unsigned short* __restrict__ xb,
    const unsigned short* __restrict__ Bct,
    const float* __restrict__ bg1, const float* __restrict__ bdr,
    const float* __restrict__ bdi,
    unsigned short* __restrict__ g1b,
    unsigned short* __restrict__ drvb, float* __restrict__ drvf)
{
    __shared__ unsigned short L[8*8192];   // 128 KiB

    const int tid  = threadIdx.x;
    const int wave = tid >> 6, lane = tid & 63;
    const int wmr  = wave >> 2;            // 0..1  (64-row group within a half)
    const int wnr  = wave & 3;             // 0..3  (32-col group within a half)
    const int row0 = blockIdx.x * 256, col0 = blockIdx.y * 256;
    const int cn = lane & 15, quad = lane >> 4;
    const int e8 = cn & 7;
    const int srow = lane >> 3;                    // staging row-in-8
    const int lksw = ((lane & 7) ^ srow) * 8;      // pre-swizzled src k offset

    const unsigned short* Ag = xb  + (size_t)row0 * DIN;
    const unsigned short* Bg = Bct + (size_t)col0 * DIN;

    f32x4 acc[8][4];
    const f32x4 z = {0.f, 0.f, 0.f, 0.f};
    #pragma unroll
    for (int i = 0; i < 8; ++i)
        #pragma unroll
        for (int j = 0; j < 4; ++j) acc[i][j] = z;

#define SLOT(b,o,h) (L + (((b)*4 + (o)*2 + (h)) * 8192))
// stage one 128x64 half-tile (2 x global_load_lds per thread-wave)
#define STAGE(b,o,h,kt,Gp) do { \
    const unsigned short* _g = (Gp) + (size_t)((h)*128 + wave*8 + srow)*DIN \
                             + (size_t)(kt)*64 + lksw; \
    unsigned short* _l = SLOT(b,o,h) + wave*512; \
    GLD_LDS(_g, _l); \
    GLD_LDS(_g + (size_t)64*DIN, _l + 4096); \
} while(0)

#define PHASE(b, ih, jh, STG, WT) do { \
    bf16x8 af[4][2], bfv[2][2]; \
    _Pragma("unroll") \
    for (int ii = 0; ii < 4; ++ii) { \
        const unsigned short* ap = SLOT(b,0,ih) + (size_t)(wmr*64 + ii*16 + cn)*64; \
        _Pragma("unroll") \
        for (int kk = 0; kk < 2; ++kk) \
            af[ii][kk] = *(const bf16x8*)(ap + ((kk*4 + quad) ^ e8)*8); \
    } \
    _Pragma("unroll") \
    for (int jj = 0; jj < 2; ++jj) { \
        const unsigned short* bp = SLOT(b,1,jh) + (size_t)(wnr*32 + jj*16 + cn)*64; \
        _Pragma("unroll") \
        for (int kk = 0; kk < 2; ++kk) \
            bfv[jj][kk] = *(const bf16x8*)(bp + ((kk*4 + quad) ^ e8)*8); \
    } \
    STG; \
    WT; \
    __builtin_amdgcn_s_barrier(); \
    asm volatile("s_waitcnt lgkmcnt(0)" ::: "memory"); \
    __builtin_amdgcn_s_setprio(1); \
    _Pragma("unroll") \
    for (int ii = 0; ii < 4; ++ii) \
        _Pragma("unroll") \
        for (int jj = 0; jj < 2; ++jj) \
            _Pragma("unroll") \
            for (int kk = 0; kk < 2; ++kk) \
                acc[(ih)*4 + ii][(jh)*2 + jj] = \
                    __builtin_amdgcn_mfma_f32_16x16x32_bf16( \
                        af[ii][kk], bfv[jj][kk], \
                        acc[(ih)*4 + ii][(jh)*2 + jj], 0, 0, 0); \
    __builtin_amdgcn_s_setprio(0); \
    __builtin_amdgcn_s_barrier(); \
} while(0)

    // prologue: tile0 (all 4 halves) + tile1 {A0, B1}
    STAGE(0,0,0, 0, Ag); STAGE(0,1,0, 0, Bg);
    STAGE(0,0,1, 0, Ag); STAGE(0,1,1, 0, Bg);
    STAGE(1,0,0, 1, Ag); STAGE(1,1,1, 1, Bg);
    asm volatile("s_waitcnt vmcnt(4)" ::: "memory");
    __builtin_amdgcn_s_barrier();

    #pragma unroll 1
    for (int it = 0; it < 8; ++it) {
        const int t1 = 2*it + 1, t2 = 2*it + 2, t3 = 2*it + 3;
        const bool pf = (it < 7);
        PHASE(0, 0, 0, { STAGE(1,0,1, t1, Ag); }, {});
        PHASE(0, 0, 1, { STAGE(1,1,0, t1, Bg); }, {});
        PHASE(0, 1, 1, { if (pf) STAGE(0,0,0, t2, Ag); }, {});
        PHASE(0, 1, 0, { if (pf) STAGE(0,1,1, t2, Bg); },
              { if (pf) asm volatile("s_waitcnt vmcnt(4)" ::: "memory");
                else    asm volatile("s_waitcnt vmcnt(0)" ::: "memory"); });
        PHASE(1, 0, 0, { if (pf) STAGE(0,0,1, t2, Ag); }, {});
        PHASE(1, 0, 1, { if (pf) STAGE(0,1,0, t2, Bg); }, {});
        PHASE(1, 1, 1, { if (pf) STAGE(1,0,0, t3, Ag); }, {});
        PHASE(1, 1, 0, { if (pf) STAGE(1,1,1, t3, Bg); },
              { if (pf) asm volatile("s_waitcnt vmcnt(4)" ::: "memory");
                else    asm volatile("s_waitcnt vmcnt(0)" ::: "memory"); });
    }
#undef PHASE
#undef STAGE
#undef SLOT

    // epilogue — (s, mat) are block-uniform (768 = 3*256, col0 % 256 == 0)
    const int s    = col0 / 768;
    const int rem  = col0 - s*768;
    const int mat  = rem >> 8;                 // 0:g1  1:dre  2:dim
    const float* bias = (mat == 0) ? bg1 : ((mat == 1) ? bdr : bdi);

    int dloc[4]; float bv[4];
    #pragma unroll
    for (int j = 0; j < 4; ++j) {
        dloc[j] = (j >> 1)*128 + wnr*32 + (j & 1)*16 + cn;
        bv[j] = bias[s*D_ + dloc[j]];
    }

    #pragma unroll
    for (int i = 0; i < 8; ++i) {
        const int m = row0 + (i >> 2)*128 + wmr*64 + (i & 3)*16 + quad*4;
        #pragma unroll
        for (int j = 0; j < 4; ++j) {
            const int d = dloc[j];
            const f32x4 v = acc[i][j];
            if (mat == 0) {
                unsigned short* gp = g1b + ((size_t)s*BT_ + m)*D_ + d;
                #pragma unroll
                for (int r = 0; r < 4; ++r)
                    gp[(size_t)r*D_] = f2bf(fmaxf(v[r] + bv[j], 0.f));
            } else {
                const size_t base = (size_t)m*(S_*2*D_) + s*2*D_
                                  + (mat == 2 ? D_ : 0) + d;
                if (DRVB) {
                    #pragma unroll
                    for (int r = 0; r < 4; ++r)
                        drvb[base + (size_t)r*(S_*2*D_)] = f2bf(v[r] + bv[j]);
                } else {
                    #pragma unroll
                    for (int r = 0; r < 4; ++r)
                        drvf[base + (size_t)r*(S_*2*D_)] = v[r] + bv[j];
                }
            }
        }
    }
}

// ---------------------------------------------------------------------------
// k2: per-s  omg = sigmoid(-(g1 @ Wg2 + bg2)) -> u16 fixed-point
// ---------------------------------------------------------------------------
__global__ __launch_bounds__(256) void k2_mfma(
    const unsigned short* __restrict__ g1b,
    const unsigned short* __restrict__ B2t,
    const float* __restrict__ bg2, unsigned short* __restrict__ omgu)
{
    __shared__ unsigned short As[128*64];
    __shared__ unsigned short Bs[128*64];

    const int tid = threadIdx.x;
    const int wave = tid >> 6, lane = tid & 63;
    const int wm = (wave >> 1) * 64, wn = (wave & 1) * 64;
    const int row0 = blockIdx.x * 128, col0 = blockIdx.y * 128;
    const int s = blockIdx.z;

    const f32x4 z = {0.f, 0.f, 0.f, 0.f};
    f32x4 acc[4][4];
    #pragma unroll
    for (int i = 0; i < 4; ++i)
        #pragma unroll
        for (int j = 0; j < 4; ++j) acc[i][j] = z;

    const unsigned short* Ag = g1b + ((size_t)s*BT_ + row0)*D_;
    const unsigned short* Bg = B2t + (size_t)s*D_*D_ + (size_t)col0*D_;
    const int lrow = lane >> 3;
    const int lksw = ((lane & 7) ^ lrow) * 8;
    const int cn   = lane & 15, quad = lane >> 4;
    const int e    = cn & 7;

    for (int k0 = 0; k0 < D_; k0 += 64) {
        #pragma unroll
        for (int t = 0; t < 4; ++t) {
            const int m0 = wave*32 + t*8;
            GLD_LDS(Ag + (size_t)(m0 + lrow)*D_ + k0 + lksw, As + m0*64);
            GLD_LDS(Bg + (size_t)(m0 + lrow)*D_ + k0 + lksw, Bs + m0*64);
        }
        __syncthreads();
        #pragma unroll
        for (int ks = 0; ks < 2; ++ks) {
            const int offs = (((ks*4 + quad) ^ e)) * 8;
            bf16x8 af[4], bfv[4];
            #pragma unroll
            for (int i = 0; i < 4; ++i)
                af[i] = *(const bf16x8*)(As + (wm + i*16 + cn)*64 + offs);
            #pragma unroll
            for (int j = 0; j < 4; ++j)
                bfv[j] = *(const bf16x8*)(Bs + (wn + j*16 + cn)*64 + offs);
            #pragma unroll
            for (int i = 0; i < 4; ++i)
                #pragma unroll
                for (int j = 0; j < 4; ++j)
                    acc[i][j] = __builtin_amdgcn_mfma_f32_16x16x32_bf16(
                        af[i], bfv[j], acc[i][j], 0, 0, 0);
        }
        __syncthreads();
    }

    const int qr = quad * 4;
    float bv[4];
    #pragma unroll
    for (int j = 0; j < 4; ++j) bv[j] = bg2[s*D_ + col0 + wn + j*16 + cn];

    #pragma unroll
    for (int i = 0; i < 4; ++i) {
        const int m = row0 + wm + i*16 + qr;
        #pragma unroll
        for (int j = 0; j < 4; ++j) {
            const int d = col0 + wn + j*16 + cn;
            const f32x4 v = acc[i][j];
            unsigned short* op = omgu + ((size_t)s*BT_ + m)*D_ + d;
            #pragma unroll
            for (int r = 0; r < 4; ++r) {
                const float om = 1.f / (1.f + __expf(v[r] + bv[j]));
                op[(size_t)r*D_] =
                    (unsigned short)fminf(om * 65536.f, 65535.f);
            }
        }
    }
}

// ---------------------------------------------------------------------------
// k3a: per-chunk summaries. 128 threads, 2 channels each, packed loads.
// ---------------------------------------------------------------------------
template<bool DRVB>
__global__ __launch_bounds__(128) void k3a_chunk(
    const unsigned short* __restrict__ omgu,
    const unsigned short* __restrict__ drvb, const float* __restrict__ drvf,
    float4* __restrict__ summ, SC sc)
{
    const int blk = blockIdx.x;
    const int c = blk & (CHUNKS-1);
    const int s = (blk >> 7) & (S_-1);
    const int b = blk >> 9;
    const int d2 = threadIdx.x;     // channels 2*d2, 2*d2+1

    const float are = sc.are[s], aim = sc.aim[s], bs = sc.bsc[s];
    float Ar[2] = {1.f,1.f}, Ai[2] = {0,0}, Hr[2] = {0,0}, Hi[2] = {0,0};
    const int t0 = c * CL;

    #pragma unroll 4
    for (int t = 0; t < CL; ++t) {
        const int bt = b*T_ + t0 + t;
        const unsigned int ov =
            *(const unsigned int*)(omgu + ((size_t)s*BT_ + bt)*D_ + 2*d2);
        const float om[2] = { u16om(ov & 0xFFFFu), u16om(ov >> 16) };
        const size_t base = (size_t)bt*(S_*2*D_) + s*2*D_ + 2*d2;
        float dre[2], dim[2];
        if (DRVB) {
            const unsigned int ur = *(const unsigned int*)(drvb + base);
            const unsigned int ui = *(const unsigned int*)(drvb + base + D_);
            dre[0] = bf2f_lo(ur); dre[1] = bf2f_hi(ur);
            dim[0] = bf2f_lo(ui); dim[1] = bf2f_hi(ui);
        } else {
            const float2 fr = *(const float2*)(drvf + base);
            const float2 fi = *(const float2*)(drvf + base + D_);
            dre[0] = fr.x; dre[1] = fr.y; dim[0] = fi.x; dim[1] = fi.y;
        }
        #pragma unroll
        for (int u = 0; u < 2; ++u) {
            const float ar = om[u]*are, ai = om[u]*aim, ob = om[u]*bs;
            const float br = ob*dre[u], bi = ob*dim[u];
            const float nHr = ar*Hr[u] - ai*Hi[u] + br;
            const float nHi = ar*Hi[u] + ai*Hr[u] + bi;
            const float nAr = ar*Ar[u] - ai*Ai[u];
            const float nAi = ar*Ai[u] + ai*Ar[u];
            Hr[u]=nHr; Hi[u]=nHi; Ar[u]=nAr; Ai[u]=nAi;
        }
    }
    const size_t so = ((size_t)(b*S_ + s)*CHUNKS + c)*D_ + 2*d2;
    summ[so]     = make_float4(Ar[0], Ai[0], Hr[0], Hi[0]);
    summ[so + 1] = make_float4(Ar[1], Ai[1], Hr[1], Hi[1]);
}

// ---------------------------------------------------------------------------
// k3b: parallel segmented scan over the 128 chunk summaries per channel.
// One block handles 2 channels; 128 threads per channel (one per chunk).
// Hillis-Steele inclusive scan over (A,H) compose, then write exclusive H.
// ---------------------------------------------------------------------------
__global__ __launch_bounds__(256) void k3b_scan(float4* __restrict__ summ)
{
    __shared__ float4 sb[2][CHUNKS];
    const int ch = threadIdx.x >> 7;               // 0..1
    const int c  = threadIdx.x & (CHUNKS-1);
    const int channel = blockIdx.x*2 + ch;         // 0..4095
    const int d = channel & (D_-1);
    const int s = (channel >> 8) & (S_-1);
    const int b = channel >> 10;
    const size_t off = ((size_t)(b*S_ + s)*CHUNKS + c)*D_ + d;

    float4 v = summ[off];
    sb[ch][c] = v;
    __syncthreads();
    #pragma unroll
    for (int st = 1; st < CHUNKS; st <<= 1) {
        float4 l;
        if (c >= st) l = sb[ch][c - st];
        __syncthreads();
        if (c >= st) {
            float4 nv;
            nv.x = l.x*v.x - l.y*v.y;              // A = A_l * A_r (complex)
            nv.y = l.x*v.y + l.y*v.x;
            nv.z = v.x*l.z - v.y*l.w + v.z;        // H = A_r*H_l + H_r
            nv.w = v.x*l.w + v.y*l.z + v.w;
            v = nv;
            sb[ch][c] = v;
        }
        __syncthreads();
    }
    float2 carry = make_float2(0.f, 0.f);          // exclusive: prefix of c-1
    if (c > 0) { const float4 p = sb[ch][c-1]; carry = make_float2(p.z, p.w); }
    *(float2*)&summ[off] = carry;
}

// ---------------------------------------------------------------------------
// k3c: final pass — redo local scan with carry, write h (fp32) to out.
// ---------------------------------------------------------------------------
template<bool DRVB>
__global__ __launch_bounds__(128) void k3c_final(
    const unsigned short* __restrict__ omgu,
    const unsigned short* __restrict__ drvb, const float* __restrict__ drvf,
    float* __restrict__ out, const float4* __restrict__ summ, SC sc)
{
    const int blk = blockIdx.x;
    const int c = blk & (CHUNKS-1);
    const int s = (blk >> 7) & (S_-1);
    const int b = blk >> 9;
    const int d2 = threadIdx.x;

    const float are = sc.are[s], aim = sc.aim[s], bs = sc.bsc[s];
    const size_t so = ((size_t)(b*S_ + s)*CHUNKS + c)*D_ + 2*d2;
    const float4 v0 = summ[so];
    const float4 v1 = summ[so + 1];
    float Hr[2] = {v0.x, v1.x}, Hi[2] = {v0.y, v1.y};
    const int t0 = c * CL;

    #pragma unroll 4
    for (int t = 0; t < CL; ++t) {
        const int bt = b*T_ + t0 + t;
        const unsigned int ov =
            *(const unsigned int*)(omgu + ((size_t)s*BT_ + bt)*D_ + 2*d2);
        const float om[2] = { u16om(ov & 0xFFFFu), u16om(ov >> 16) };
        const size_t base = (size_t)bt*(S_*2*D_) + s*2*D_ + 2*d2;
        float dre[2], dim[2];
        if (DRVB) {
            const unsigned int ur = *(const unsigned int*)(drvb + base);
            const unsigned int ui = *(const unsigned int*)(drvb + base + D_);
            dre[0] = bf2f_lo(ur); dre[1] = bf2f_hi(ur);
            dim[0] = bf2f_lo(ui); dim[1] = bf2f_hi(ui);
        } else {
            const float2 fr = *(const float2*)(drvf + base);
            const float2 fi = *(const float2*)(drvf + base + D_);
            dre[0] = fr.x; dre[1] = fr.y; dim[0] = fi.x; dim[1] = fi.y;
        }
        #pragma unroll
        for (int u = 0; u < 2; ++u) {
            const float ar = om[u]*are, ai = om[u]*aim, ob = om[u]*bs;
            const float br = ob*dre[u], bi = ob*dim[u];
            const float nHr = ar*Hr[u] - ai*Hi[u] + br;
            const float nHi = ar*Hi[u] + ai*Hr[u] + bi;
            Hr[u]=nHr; Hi[u]=nHi;
        }
        *(float2*)(out + base)      = make_float2(Hr[0], Hr[1]);
        *(float2*)(out + base + D_) = make_float2(Hi[0], Hi[1]);
    }
}

// ---------------------------------------------------------------------------
extern "C" void kernel_launch(void* const* d_in, const int* in_sizes, int n_in,
                              void* d_out, int out_size, void* d_ws, size_t ws_size,
                              hipStream_t stream)
{
    const float* x   = (const float*)d_in[0];
    const float* Wg1 = (const float*)d_in[1];
    const float* bg1 = (const float*)d_in[2];
    const float* Wg2 = (const float*)d_in[3];
    const float* bg2 = (const float*)d_in[4];
    const float* Wdr = (const float*)d_in[5];
    const float* bdr = (const float*)d_in[6];
    const float* Wdi = (const float*)d_in[7];
    const float* bdi = (const float*)d_in[8];
    float* out = (float*)d_out;

    // workspace layout (141.0 MB total):
    //   [0, 33.5M)      g1b (k1..k2)  -> summ (k3a..k3c)       alias OK
    //   [33.5M, 34.1M)  B2t (conv..k2)
    //   [34.1M, 67.6M)  xb  (conv..k1) -> omgu (k2..k3c)       alias OK
    //   [67.6M, 73.9M)  Bct (conv..k1)
    //   [73.9M, 141.0M) drvb bf16 (k1..k3c)   [if ws fits, else fp32 in out]
    char* ws = (char*)d_ws;
    unsigned short* g1b  = (unsigned short*)(ws + 0);
    float4*         summ = (float4*)(ws + 0);
    unsigned short* B2t  = (unsigned short*)(ws + 33554432);
    unsigned short* xb   = (unsigned short*)(ws + 34078720);
    unsigned short* omgu = (unsigned short*)(ws + 34078720);
    unsigned short* Bct  = (unsigned short*)(ws + 67633152);
    unsigned short* drvb = (unsigned short*)(ws + 73924608);
    const bool drv_bf16 = ws_size >= (size_t)73924608 + 67108864;

    SC sc;
    {
        const double r[S_]  = {1.0, 0.999, 0.9495, 0.9};
        const double th[S_] = {0.0, 0.01, 0.505, 1.0};
        for (int s = 0; s < S_; ++s) {
            sc.are[s] = (float)(r[s] * cos(th[s]));
            sc.aim[s] = (float)(r[s] * sin(th[s]));
            sc.bsc[s] = (r[s] >= 1.0) ? (float)(1.0/16.0) : (float)(1.0 - r[s]);
        }
    }

    // conversions
    kconv_x<<<(BT_*DIN)/1024, 256, 0, stream>>>(x, xb);
    kconv_w3<<<dim3(32,8,12), 256, 0, stream>>>(Wg1, Wdr, Wdi, Bct);
    kconv_w<<<dim3(8,8,S_),  256, 0, stream>>>(Wg2, B2t, D_, D_, (size_t)D_*D_);

    // GEMMs
    if (drv_bf16)
        k1_8p<true><<<dim3(BT_/256, GN/256), 512, 0, stream>>>(
            xb, Bct, bg1, bdr, bdi, g1b, drvb, out);
    else
        k1_8p<false><<<dim3(BT_/256, GN/256), 512, 0, stream>>>(
            xb, Bct, bg1, bdr, bdi, g1b, drvb, out);
    k2_mfma<<<dim3(BT_/128, D_/128, S_), 256, 0, stream>>>(g1b, B2t, bg2, omgu);

    // scan
    if (drv_bf16) {
        k3a_chunk<true><<<B_*S_*CHUNKS, 128, 0, stream>>>(omgu, drvb, out, summ, sc);
        k3b_scan       <<<(B_*S_*D_)/2, 256, 0, stream>>>(summ);
        k3c_final<true><<<B_*S_*CHUNKS, 128, 0, stream>>>(omgu, drvb, out, out, summ, sc);
    } else {
        k3a_chunk<false><<<B_*S_*CHUNKS, 128, 0, stream>>>(omgu, drvb, out, summ, sc);
        k3b_scan        <<<(B_*S_*D_)/2, 256, 0, stream>>>(summ);
        k3c_final<false><<<B_*S_*CHUNKS, 128, 0, stream>>>(omgu, drvb, out, out, summ, sc);
    }
}

// Round 2
// 399.906 us; speedup vs baseline: 1.0738x; 1.0168x over previous
//
#include <hip/hip_runtime.h>
#include <cmath>

#define S_   4
#define DIN  1024
#define D_   256
#define B_   4
#define T_   4096
#define BT_  (B_*T_)
#define GN   (S_*3*D_)     // 3072 concat N for the big GEMM
#define CHUNKS 128
#define CL   (T_/CHUNKS)   // 32

typedef short bf16x8 __attribute__((ext_vector_type(8)));
typedef float f32x4  __attribute__((ext_vector_type(4)));

struct SC { float are[S_]; float aim[S_]; float bsc[S_]; };

__device__ inline unsigned short f2bf(float f) {
    unsigned int u = __builtin_bit_cast(unsigned int, f);
    unsigned int r = (u + 0x7FFFu + ((u >> 16) & 1u)) >> 16;
    return (unsigned short)r;
}
__device__ inline float bf2f_lo(unsigned int u) {
    return __builtin_bit_cast(float, u << 16);
}
__device__ inline float bf2f_hi(unsigned int u) {
    return __builtin_bit_cast(float, u & 0xFFFF0000u);
}
// omg u16 fixed-point decode: (u + 0.5) / 65536
__device__ inline float u16om(unsigned int u) {
    return ((float)u + 0.5f) * (1.f/65536.f);
}

#define GLD_LDS(gp, lp) \
    __builtin_amdgcn_global_load_lds( \
        (const __attribute__((address_space(1))) void*)(gp), \
        (__attribute__((address_space(3))) void*)(lp), 16, 0, 0)

// ---------------------------------------------------------------------------
// x fp32 -> bf16
// ---------------------------------------------------------------------------
__global__ __launch_bounds__(256) void kconv_x(
    const float* __restrict__ x, unsigned short* __restrict__ xb)
{
    const size_t i = ((size_t)blockIdx.x*256 + threadIdx.x)*4;
    const float4 v = *(const float4*)(x + i);
    ushort4 o;
    o.x = f2bf(v.x); o.y = f2bf(v.y); o.z = f2bf(v.z); o.w = f2bf(v.w);
    *(ushort4*)(xb + i) = o;
}

// ---------------------------------------------------------------------------
// Weight transpose+convert (Wg2 only): src [S][K][N] fp32 -> [S][N][K] bf16
// ---------------------------------------------------------------------------
__global__ __launch_bounds__(256) void kconv_w(
    const float* __restrict__ src, unsigned short* __restrict__ dst,
    int K, int N, size_t dst_s_stride)
{
    __shared__ float t[32][33];
    const int k0 = blockIdx.x*32, n0 = blockIdx.y*32, s = blockIdx.z;
    const float* sp = src + (size_t)s*K*N;
    unsigned short* dp = dst + (size_t)s*dst_s_stride;
    const int c = threadIdx.x & 31, r0 = threadIdx.x >> 5;
    #pragma unroll
    for (int p = 0; p < 4; ++p)
        t[r0 + p*8][c] = sp[(size_t)(k0 + r0 + p*8)*N + n0 + c];
    __syncthreads();
    #pragma unroll
    for (int p = 0; p < 4; ++p)
        dp[(size_t)(n0 + r0 + p*8)*K + k0 + c] = f2bf(t[c][r0 + p*8]);
}

// ---------------------------------------------------------------------------
// Merged transpose+convert for the three DIN x D_ weights -> Bct layout.
// z = widx*S_ + s; widx 0:Wg1 1:Wdr 2:Wdi
// ---------------------------------------------------------------------------
__global__ __launch_bounds__(256) void kconv_w3(
    const float* __restrict__ Wg1, const float* __restrict__ Wdr,
    const float* __restrict__ Wdi, unsigned short* __restrict__ dst)
{
    __shared__ float t[32][33];
    const int z = blockIdx.z;
    const int widx = z >> 2, s = z & 3;
    const float* src = (widx == 0) ? Wg1 : ((widx == 1) ? Wdr : Wdi);
    const float* sp = src + (size_t)s*DIN*D_;
    unsigned short* dp = dst + (size_t)s*768*DIN + (size_t)widx*D_*DIN;
    const int k0 = blockIdx.x*32, n0 = blockIdx.y*32;
    const int c = threadIdx.x & 31, r0 = threadIdx.x >> 5;
    #pragma unroll
    for (int p = 0; p < 4; ++p)
        t[r0 + p*8][c] = sp[(size_t)(k0 + r0 + p*8)*D_ + n0 + c];
    __syncthreads();
    #pragma unroll
    for (int p = 0; p < 4; ++p)
        dp[(size_t)(n0 + r0 + p*8)*DIN + k0 + c] = f2bf(t[c][r0 + p*8]);
}

// ---------------------------------------------------------------------------
// k1_8p: C[16384][3072] = xb * Bct^T, 256x256 tile, BK=64, 8 waves (2M x 4N),
// 8-phase schedule, counted vmcnt (never 0 in steady state), st-swizzled LDS.
// LDS: 8 half-tile slots of 16 KiB: [buf][op][half] (128 rows x 64 k bf16).
// Quadrant order per K-tile: (ih,jh) = (0,0),(0,1),(1,1),(1,0) — consecutive
// phases share ih or jh, so A/B fragments persist in registers:
//   reads/phase = 12,4,8,4 (56/iter instead of 96; -42% LDS drain).
// Issue schedule: P1:A1[t+1] P2:B0[t+1] P3:A0[t+2] P4:B1[t+2]
//                 P5:A1[t+2] P6:B0[t+2] P7:A0[t+3] P8:B1[t+3]
// Waits: vmcnt(4) at P4 and P8, vmcnt(0) in the last iteration.
// ---------------------------------------------------------------------------
template<bool DRVB>
__global__ __launch_bounds__(512, 2) void k1_8p(
    const unsigned short* __restrict__ xb,
    const unsigned short* __restrict__ Bct,
    const float* __restrict__ bg1, const float* __restrict__ bdr,
    const float* __restrict__ bdi,
    unsigned short* __restrict__ g1b,
    unsigned short* __restrict__ drvb, float* __restrict__ drvf)
{
    __shared__ unsigned short L[8*8192];   // 128 KiB

    const int tid  = threadIdx.x;
    const int wave = tid >> 6, lane = tid & 63;
    const int wmr  = wave >> 2;            // 0..1  (64-row group within a half)
    const int wnr  = wave & 3;             // 0..3  (32-col group within a half)
    const int row0 = blockIdx.x * 256, col0 = blockIdx.y * 256;
    const int cn = lane & 15, quad = lane >> 4;
    const int e8 = cn & 7;
    const int srow = lane >> 3;                    // staging row-in-8
    const int lksw = ((lane & 7) ^ srow) * 8;      // pre-swizzled src k offset

    const unsigned short* Ag = xb  + (size_t)row0 * DIN;
    const unsigned short* Bg = Bct + (size_t)col0 * DIN;

    f32x4 acc[8][4];
    const f32x4 z = {0.f, 0.f, 0.f, 0.f};
    #pragma unroll
    for (int i = 0; i < 8; ++i)
        #pragma unroll
        for (int j = 0; j < 4; ++j) acc[i][j] = z;

    bf16x8 af[4][2];    // persistent A fragments (current ih)
    bf16x8 bfv[2][2];   // persistent B fragments (current jh)

#define SLOT(b,o,h) (L + (((b)*4 + (o)*2 + (h)) * 8192))
// stage one 128x64 half-tile (2 x global_load_lds per thread-wave)
#define STAGE(b,o,h,kt,Gp) do { \
    const unsigned short* _g = (Gp) + (size_t)((h)*128 + wave*8 + srow)*DIN \
                             + (size_t)(kt)*64 + lksw; \
    unsigned short* _l = SLOT(b,o,h) + wave*512; \
    GLD_LDS(_g, _l); \
    GLD_LDS(_g + (size_t)64*DIN, _l + 4096); \
} while(0)

#define PHASE(b, ih, jh, LA, LB, STG, WT) do { \
    if (LA) { \
        _Pragma("unroll") \
        for (int ii = 0; ii < 4; ++ii) { \
            const unsigned short* ap = SLOT(b,0,ih) + (size_t)(wmr*64 + ii*16 + cn)*64; \
            _Pragma("unroll") \
            for (int kk = 0; kk < 2; ++kk) \
                af[ii][kk] = *(const bf16x8*)(ap + ((kk*4 + quad) ^ e8)*8); \
        } \
    } \
    if (LB) { \
        _Pragma("unroll") \
        for (int jj = 0; jj < 2; ++jj) { \
            const unsigned short* bp = SLOT(b,1,jh) + (size_t)(wnr*32 + jj*16 + cn)*64; \
            _Pragma("unroll") \
            for (int kk = 0; kk < 2; ++kk) \
                bfv[jj][kk] = *(const bf16x8*)(bp + ((kk*4 + quad) ^ e8)*8); \
        } \
    } \
    STG; \
    WT; \
    __builtin_amdgcn_s_barrier(); \
    asm volatile("s_waitcnt lgkmcnt(0)" ::: "memory"); \
    __builtin_amdgcn_s_setprio(1); \
    _Pragma("unroll") \
    for (int ii = 0; ii < 4; ++ii) \
        _Pragma("unroll") \
        for (int jj = 0; jj < 2; ++jj) \
            _Pragma("unroll") \
            for (int kk = 0; kk < 2; ++kk) \
                acc[(ih)*4 + ii][(jh)*2 + jj] = \
                    __builtin_amdgcn_mfma_f32_16x16x32_bf16( \
                        af[ii][kk], bfv[jj][kk], \
                        acc[(ih)*4 + ii][(jh)*2 + jj], 0, 0, 0); \
    __builtin_amdgcn_s_setprio(0); \
    __builtin_amdgcn_s_barrier(); \
} while(0)

    // prologue: tile0 (all 4 halves) + tile1 {A0, B1}
    STAGE(0,0,0, 0, Ag); STAGE(0,1,0, 0, Bg);
    STAGE(0,0,1, 0, Ag); STAGE(0,1,1, 0, Bg);
    STAGE(1,0,0, 1, Ag); STAGE(1,1,1, 1, Bg);
    asm volatile("s_waitcnt vmcnt(4)" ::: "memory");
    __builtin_amdgcn_s_barrier();

    #pragma unroll 1
    for (int it = 0; it < 8; ++it) {
        const int t1 = 2*it + 1, t2 = 2*it + 2, t3 = 2*it + 3;
        const bool pf = (it < 7);
        PHASE(0, 0, 0, 1, 1, { STAGE(1,0,1, t1, Ag); }, {});
        PHASE(0, 0, 1, 0, 1, { STAGE(1,1,0, t1, Bg); }, {});
        PHASE(0, 1, 1, 1, 0, { if (pf) STAGE(0,0,0, t2, Ag); }, {});
        PHASE(0, 1, 0, 0, 1, { if (pf) STAGE(0,1,1, t2, Bg); },
              { if (pf) asm volatile("s_waitcnt vmcnt(4)" ::: "memory");
                else    asm volatile("s_waitcnt vmcnt(0)" ::: "memory"); });
        PHASE(1, 0, 0, 1, 1, { if (pf) STAGE(0,0,1, t2, Ag); }, {});
        PHASE(1, 0, 1, 0, 1, { if (pf) STAGE(0,1,0, t2, Bg); }, {});
        PHASE(1, 1, 1, 1, 0, { if (pf) STAGE(1,0,0, t3, Ag); }, {});
        PHASE(1, 1, 0, 0, 1, { if (pf) STAGE(1,1,1, t3, Bg); },
              { if (pf) asm volatile("s_waitcnt vmcnt(4)" ::: "memory");
                else    asm volatile("s_waitcnt vmcnt(0)" ::: "memory"); });
    }
#undef PHASE
#undef STAGE
#undef SLOT

    // epilogue — (s, mat) are block-uniform (768 = 3*256, col0 % 256 == 0)
    const int s    = col0 / 768;
    const int rem  = col0 - s*768;
    const int mat  = rem >> 8;                 // 0:g1  1:dre  2:dim
    const float* bias = (mat == 0) ? bg1 : ((mat == 1) ? bdr : bdi);

    int dloc[4]; float bv[4];
    #pragma unroll
    for (int j = 0; j < 4; ++j) {
        dloc[j] = (j >> 1)*128 + wnr*32 + (j & 1)*16 + cn;
        bv[j] = bias[s*D_ + dloc[j]];
    }

    #pragma unroll
    for (int i = 0; i < 8; ++i) {
        const int m = row0 + (i >> 2)*128 + wmr*64 + (i & 3)*16 + quad*4;
        #pragma unroll
        for (int j = 0; j < 4; ++j) {
            const int d = dloc[j];
            const f32x4 v = acc[i][j];
            if (mat == 0) {
                unsigned short* gp = g1b + ((size_t)s*BT_ + m)*D_ + d;
                #pragma unroll
                for (int r = 0; r < 4; ++r)
                    gp[(size_t)r*D_] = f2bf(fmaxf(v[r] + bv[j], 0.f));
            } else {
                const size_t base = (size_t)m*(S_*2*D_) + s*2*D_
                                  + (mat == 2 ? D_ : 0) + d;
                if (DRVB) {
                    #pragma unroll
                    for (int r = 0; r < 4; ++r)
                        drvb[base + (size_t)r*(S_*2*D_)] = f2bf(v[r] + bv[j]);
                } else {
                    #pragma unroll
                    for (int r = 0; r < 4; ++r)
                        drvf[base + (size_t)r*(S_*2*D_)] = v[r] + bv[j];
                }
            }
        }
    }
}

// ---------------------------------------------------------------------------
// k2: per-s  omg = sigmoid(-(g1 @ Wg2 + bg2)) -> u16 fixed-point
// ---------------------------------------------------------------------------
__global__ __launch_bounds__(256) void k2_mfma(
    const unsigned short* __restrict__ g1b,
    const unsigned short* __restrict__ B2t,
    const float* __restrict__ bg2, unsigned short* __restrict__ omgu)
{
    __shared__ unsigned short As[128*64];
    __shared__ unsigned short Bs[128*64];

    const int tid = threadIdx.x;
    const int wave = tid >> 6, lane = tid & 63;
    const int wm = (wave >> 1) * 64, wn = (wave & 1) * 64;
    const int row0 = blockIdx.x * 128, col0 = blockIdx.y * 128;
    const int s = blockIdx.z;

    const f32x4 z = {0.f, 0.f, 0.f, 0.f};
    f32x4 acc[4][4];
    #pragma unroll
    for (int i = 0; i < 4; ++i)
        #pragma unroll
        for (int j = 0; j < 4; ++j) acc[i][j] = z;

    const unsigned short* Ag = g1b + ((size_t)s*BT_ + row0)*D_;
    const unsigned short* Bg = B2t + (size_t)s*D_*D_ + (size_t)col0*D_;
    const int lrow = lane >> 3;
    const int lksw = ((lane & 7) ^ lrow) * 8;
    const int cn   = lane & 15, quad = lane >> 4;
    const int e    = cn & 7;

    for (int k0 = 0; k0 < D_; k0 += 64) {
        #pragma unroll
        for (int t = 0; t < 4; ++t) {
            const int m0 = wave*32 + t*8;
            GLD_LDS(Ag + (size_t)(m0 + lrow)*D_ + k0 + lksw, As + m0*64);
            GLD_LDS(Bg + (size_t)(m0 + lrow)*D_ + k0 + lksw, Bs + m0*64);
        }
        __syncthreads();
        #pragma unroll
        for (int ks = 0; ks < 2; ++ks) {
            const int offs = (((ks*4 + quad) ^ e)) * 8;
            bf16x8 af[4], bfv[4];
            #pragma unroll
            for (int i = 0; i < 4; ++i)
                af[i] = *(const bf16x8*)(As + (wm + i*16 + cn)*64 + offs);
            #pragma unroll
            for (int j = 0; j < 4; ++j)
                bfv[j] = *(const bf16x8*)(Bs + (wn + j*16 + cn)*64 + offs);
            #pragma unroll
            for (int i = 0; i < 4; ++i)
                #pragma unroll
                for (int j = 0; j < 4; ++j)
                    acc[i][j] = __builtin_amdgcn_mfma_f32_16x16x32_bf16(
                        af[i], bfv[j], acc[i][j], 0, 0, 0);
        }
        __syncthreads();
    }

    const int qr = quad * 4;
    float bv[4];
    #pragma unroll
    for (int j = 0; j < 4; ++j) bv[j] = bg2[s*D_ + col0 + wn + j*16 + cn];

    #pragma unroll
    for (int i = 0; i < 4; ++i) {
        const int m = row0 + wm + i*16 + qr;
        #pragma unroll
        for (int j = 0; j < 4; ++j) {
            const int d = col0 + wn + j*16 + cn;
            const f32x4 v = acc[i][j];
            unsigned short* op = omgu + ((size_t)s*BT_ + m)*D_ + d;
            #pragma unroll
            for (int r = 0; r < 4; ++r) {
                const float om = 1.f / (1.f + __expf(v[r] + bv[j]));
                op[(size_t)r*D_] =
                    (unsigned short)fminf(om * 65536.f, 65535.f);
            }
        }
    }
}

// ---------------------------------------------------------------------------
// k3a: per-chunk summaries. 128 threads, 2 channels each, packed loads.
// ---------------------------------------------------------------------------
template<bool DRVB>
__global__ __launch_bounds__(128) void k3a_chunk(
    const unsigned short* __restrict__ omgu,
    const unsigned short* __restrict__ drvb, const float* __restrict__ drvf,
    float4* __restrict__ summ, SC sc)
{
    const int blk = blockIdx.x;
    const int c = blk & (CHUNKS-1);
    const int s = (blk >> 7) & (S_-1);
    const int b = blk >> 9;
    const int d2 = threadIdx.x;     // channels 2*d2, 2*d2+1

    const float are = sc.are[s], aim = sc.aim[s], bs = sc.bsc[s];
    float Ar[2] = {1.f,1.f}, Ai[2] = {0,0}, Hr[2] = {0,0}, Hi[2] = {0,0};
    const int t0 = c * CL;

    #pragma unroll 4
    for (int t = 0; t < CL; ++t) {
        const int bt = b*T_ + t0 + t;
        const unsigned int ov =
            *(const unsigned int*)(omgu + ((size_t)s*BT_ + bt)*D_ + 2*d2);
        const float om[2] = { u16om(ov & 0xFFFFu), u16om(ov >> 16) };
        const size_t base = (size_t)bt*(S_*2*D_) + s*2*D_ + 2*d2;
        float dre[2], dim[2];
        if (DRVB) {
            const unsigned int ur = *(const unsigned int*)(drvb + base);
            const unsigned int ui = *(const unsigned int*)(drvb + base + D_);
            dre[0] = bf2f_lo(ur); dre[1] = bf2f_hi(ur);
            dim[0] = bf2f_lo(ui); dim[1] = bf2f_hi(ui);
        } else {
            const float2 fr = *(const float2*)(drvf + base);
            const float2 fi = *(const float2*)(drvf + base + D_);
            dre[0] = fr.x; dre[1] = fr.y; dim[0] = fi.x; dim[1] = fi.y;
        }
        #pragma unroll
        for (int u = 0; u < 2; ++u) {
            const float ar = om[u]*are, ai = om[u]*aim, ob = om[u]*bs;
            const float br = ob*dre[u], bi = ob*dim[u];
            const float nHr = ar*Hr[u] - ai*Hi[u] + br;
            const float nHi = ar*Hi[u] + ai*Hr[u] + bi;
            const float nAr = ar*Ar[u] - ai*Ai[u];
            const float nAi = ar*Ai[u] + ai*Ar[u];
            Hr[u]=nHr; Hi[u]=nHi; Ar[u]=nAr; Ai[u]=nAi;
        }
    }
    const size_t so = ((size_t)(b*S_ + s)*CHUNKS + c)*D_ + 2*d2;
    summ[so]     = make_float4(Ar[0], Ai[0], Hr[0], Hi[0]);
    summ[so + 1] = make_float4(Ar[1], Ai[1], Hr[1], Hi[1]);
}

// ---------------------------------------------------------------------------
// k3b: parallel segmented scan over the 128 chunk summaries per channel.
// One block handles 2 channels; 128 threads per channel (one per chunk).
// Hillis-Steele inclusive scan over (A,H) compose, then write exclusive H.
// ---------------------------------------------------------------------------
__global__ __launch_bounds__(256) void k3b_scan(float4* __restrict__ summ)
{
    __shared__ float4 sb[2][CHUNKS];
    const int ch = threadIdx.x >> 7;               // 0..1
    const int c  = threadIdx.x & (CHUNKS-1);
    const int channel = blockIdx.x*2 + ch;         // 0..4095
    const int d = channel & (D_-1);
    const int s = (channel >> 8) & (S_-1);
    const int b = channel >> 10;
    const size_t off = ((size_t)(b*S_ + s)*CHUNKS + c)*D_ + d;

    float4 v = summ[off];
    sb[ch][c] = v;
    __syncthreads();
    #pragma unroll
    for (int st = 1; st < CHUNKS; st <<= 1) {
        float4 l;
        if (c >= st) l = sb[ch][c - st];
        __syncthreads();
        if (c >= st) {
            float4 nv;
            nv.x = l.x*v.x - l.y*v.y;              // A = A_l * A_r (complex)
            nv.y = l.x*v.y + l.y*v.x;
            nv.z = v.x*l.z - v.y*l.w + v.z;        // H = A_r*H_l + H_r
            nv.w = v.x*l.w + v.y*l.z + v.w;
            v = nv;
            sb[ch][c] = v;
        }
        __syncthreads();
    }
    float2 carry = make_float2(0.f, 0.f);          // exclusive: prefix of c-1
    if (c > 0) { const float4 p = sb[ch][c-1]; carry = make_float2(p.z, p.w); }
    *(float2*)&summ[off] = carry;
}

// ---------------------------------------------------------------------------
// k3c: final pass — redo local scan with carry, write h (fp32) to out.
// ---------------------------------------------------------------------------
template<bool DRVB>
__global__ __launch_bounds__(128) void k3c_final(
    const unsigned short* __restrict__ omgu,
    const unsigned short* __restrict__ drvb, const float* __restrict__ drvf,
    float* __restrict__ out, const float4* __restrict__ summ, SC sc)
{
    const int blk = blockIdx.x;
    const int c = blk & (CHUNKS-1);
    const int s = (blk >> 7) & (S_-1);
    const int b = blk >> 9;
    const int d2 = threadIdx.x;

    const float are = sc.are[s], aim = sc.aim[s], bs = sc.bsc[s];
    const size_t so = ((size_t)(b*S_ + s)*CHUNKS + c)*D_ + 2*d2;
    const float4 v0 = summ[so];
    const float4 v1 = summ[so + 1];
    float Hr[2] = {v0.x, v1.x}, Hi[2] = {v0.y, v1.y};
    const int t0 = c * CL;

    #pragma unroll 4
    for (int t = 0; t < CL; ++t) {
        const int bt = b*T_ + t0 + t;
        const unsigned int ov =
            *(const unsigned int*)(omgu + ((size_t)s*BT_ + bt)*D_ + 2*d2);
        const float om[2] = { u16om(ov & 0xFFFFu), u16om(ov >> 16) };
        const size_t base = (size_t)bt*(S_*2*D_) + s*2*D_ + 2*d2;
        float dre[2], dim[2];
        if (DRVB) {
            const unsigned int ur = *(const unsigned int*)(drvb + base);
            const unsigned int ui = *(const unsigned int*)(drvb + base + D_);
            dre[0] = bf2f_lo(ur); dre[1] = bf2f_hi(ur);
            dim[0] = bf2f_lo(ui); dim[1] = bf2f_hi(ui);
        } else {
            const float2 fr = *(const float2*)(drvf + base);
            const float2 fi = *(const float2*)(drvf + base + D_);
            dre[0] = fr.x; dre[1] = fr.y; dim[0] = fi.x; dim[1] = fi.y;
        }
        #pragma unroll
        for (int u = 0; u < 2; ++u) {
            const float ar = om[u]*are, ai = om[u]*aim, ob = om[u]*bs;
            const float br = ob*dre[u], bi = ob*dim[u];
            const float nHr = ar*Hr[u] - ai*Hi[u] + br;
            const float nHi = ar*Hi[u] + ai*Hr[u] + bi;
            Hr[u]=nHr; Hi[u]=nHi;
        }
        *(float2*)(out + base)      = make_float2(Hr[0], Hr[1]);
        *(float2*)(out + base + D_) = make_float2(Hi[0], Hi[1]);
    }
}

// ---------------------------------------------------------------------------
extern "C" void kernel_launch(void* const* d_in, const int* in_sizes, int n_in,
                              void* d_out, int out_size, void* d_ws, size_t ws_size,
                              hipStream_t stream)
{
    const float* x   = (const float*)d_in[0];
    const float* Wg1 = (const float*)d_in[1];
    const float* bg1 = (const float*)d_in[2];
    const float* Wg2 = (const float*)d_in[3];
    const float* bg2 = (const float*)d_in[4];
    const float* Wdr = (const float*)d_in[5];
    const float* bdr = (const float*)d_in[6];
    const float* Wdi = (const float*)d_in[7];
    const float* bdi = (const float*)d_in[8];
    float* out = (float*)d_out;

    // workspace layout (141.0 MB total):
    //   [0, 33.5M)      g1b (k1..k2)  -> summ (k3a..k3c)       alias OK
    //   [33.5M, 34.1M)  B2t (conv..k2)
    //   [34.1M, 67.6M)  xb  (conv..k1) -> omgu (k2..k3c)       alias OK
    //   [67.6M, 73.9M)  Bct (conv..k1)
    //   [73.9M, 141.0M) drvb bf16 (k1..k3c)   [if ws fits, else fp32 in out]
    char* ws = (char*)d_ws;
    unsigned short* g1b  = (unsigned short*)(ws + 0);
    float4*         summ = (float4*)(ws + 0);
    unsigned short* B2t  = (unsigned short*)(ws + 33554432);
    unsigned short* xb   = (unsigned short*)(ws + 34078720);
    unsigned short* omgu = (unsigned short*)(ws + 34078720);
    unsigned short* Bct  = (unsigned short*)(ws + 67633152);
    unsigned short* drvb = (unsigned short*)(ws + 73924608);
    const bool drv_bf16 = ws_size >= (size_t)73924608 + 67108864;

    SC sc;
    {
        const double r[S_]  = {1.0, 0.999, 0.9495, 0.9};
        const double th[S_] = {0.0, 0.01, 0.505, 1.0};
        for (int s = 0; s < S_; ++s) {
            sc.are[s] = (float)(r[s] * cos(th[s]));
            sc.aim[s] = (float)(r[s] * sin(th[s]));
            sc.bsc[s] = (r[s] >= 1.0) ? (float)(1.0/16.0) : (float)(1.0 - r[s]);
        }
    }

    // conversions
    kconv_x<<<(BT_*DIN)/1024, 256, 0, stream>>>(x, xb);
    kconv_w3<<<dim3(32,8,12), 256, 0, stream>>>(Wg1, Wdr, Wdi, Bct);
    kconv_w<<<dim3(8,8,S_),  256, 0, stream>>>(Wg2, B2t, D_, D_, (size_t)D_*D_);

    // GEMMs
    if (drv_bf16)
        k1_8p<true><<<dim3(BT_/256, GN/256), 512, 0, stream>>>(
            xb, Bct, bg1, bdr, bdi, g1b, drvb, out);
    else
        k1_8p<false><<<dim3(BT_/256, GN/256), 512, 0, stream>>>(
            xb, Bct, bg1, bdr, bdi, g1b, drvb, out);
    k2_mfma<<<dim3(BT_/128, D_/128, S_), 256, 0, stream>>>(g1b, B2t, bg2, omgu);

    // scan
    if (drv_bf16) {
        k3a_chunk<true><<<B_*S_*CHUNKS, 128, 0, stream>>>(omgu, drvb, out, summ, sc);
        k3b_scan       <<<(B_*S_*D_)/2, 256, 0, stream>>>(summ);
        k3c_final<true><<<B_*S_*CHUNKS, 128, 0, stream>>>(omgu, drvb, out, out, summ, sc);
    } else {
        k3a_chunk<false><<<B_*S_*CHUNKS, 128, 0, stream>>>(omgu, drvb, out, summ, sc);
        k3b_scan        <<<(B_*S_*D_)/2, 256, 0, stream>>>(summ);
        k3c_final<false><<<B_*S_*CHUNKS, 128, 0, stream>>>(omgu, drvb, out, out, summ, sc);
    }
}

// Round 3
// 393.818 us; speedup vs baseline: 1.0904x; 1.0155x over previous
//
#include <hip/hip_runtime.h>
#include <hip/hip_cooperative_groups.h>
#include <cmath>

#define S_   4
#define DIN  1024
#define D_   256
#define B_   4
#define T_   4096
#define BT_  (B_*T_)
#define GN   (S_*3*D_)     // 3072 concat N for the big GEMM
#define CHUNKS 128
#define CL   (T_/CHUNKS)   // 32

typedef short bf16x8 __attribute__((ext_vector_type(8)));
typedef float f32x4  __attribute__((ext_vector_type(4)));

struct SC { float are[S_]; float aim[S_]; float bsc[S_]; };

__device__ inline unsigned short f2bf(float f) {
    unsigned int u = __builtin_bit_cast(unsigned int, f);
    unsigned int r = (u + 0x7FFFu + ((u >> 16) & 1u)) >> 16;
    return (unsigned short)r;
}
__device__ inline float bf2f_lo(unsigned int u) {
    return __builtin_bit_cast(float, u << 16);
}
__device__ inline float bf2f_hi(unsigned int u) {
    return __builtin_bit_cast(float, u & 0xFFFF0000u);
}
// omg u16 fixed-point decode: (u + 0.5) / 65536
__device__ inline float u16om(unsigned int u) {
    return ((float)u + 0.5f) * (1.f/65536.f);
}

#define GLD_LDS(gp, lp) \
    __builtin_amdgcn_global_load_lds( \
        (const __attribute__((address_space(1))) void*)(gp), \
        (__attribute__((address_space(3))) void*)(lp), 16, 0, 0)

// ---------------------------------------------------------------------------
// x fp32 -> bf16
// ---------------------------------------------------------------------------
__global__ __launch_bounds__(256) void kconv_x(
    const float* __restrict__ x, unsigned short* __restrict__ xb)
{
    const size_t i = ((size_t)blockIdx.x*256 + threadIdx.x)*4;
    const float4 v = *(const float4*)(x + i);
    ushort4 o;
    o.x = f2bf(v.x); o.y = f2bf(v.y); o.z = f2bf(v.z); o.w = f2bf(v.w);
    *(ushort4*)(xb + i) = o;
}

// ---------------------------------------------------------------------------
// Weight transpose+convert (Wg2 only): src [S][K][N] fp32 -> [S][N][K] bf16
// ---------------------------------------------------------------------------
__global__ __launch_bounds__(256) void kconv_w(
    const float* __restrict__ src, unsigned short* __restrict__ dst,
    int K, int N, size_t dst_s_stride)
{
    __shared__ float t[32][33];
    const int k0 = blockIdx.x*32, n0 = blockIdx.y*32, s = blockIdx.z;
    const float* sp = src + (size_t)s*K*N;
    unsigned short* dp = dst + (size_t)s*dst_s_stride;
    const int c = threadIdx.x & 31, r0 = threadIdx.x >> 5;
    #pragma unroll
    for (int p = 0; p < 4; ++p)
        t[r0 + p*8][c] = sp[(size_t)(k0 + r0 + p*8)*N + n0 + c];
    __syncthreads();
    #pragma unroll
    for (int p = 0; p < 4; ++p)
        dp[(size_t)(n0 + r0 + p*8)*K + k0 + c] = f2bf(t[c][r0 + p*8]);
}

// ---------------------------------------------------------------------------
// Merged transpose+convert for the three DIN x D_ weights -> Bct layout.
// z = widx*S_ + s; widx 0:Wg1 1:Wdr 2:Wdi
// ---------------------------------------------------------------------------
__global__ __launch_bounds__(256) void kconv_w3(
    const float* __restrict__ Wg1, const float* __restrict__ Wdr,
    const float* __restrict__ Wdi, unsigned short* __restrict__ dst)
{
    __shared__ float t[32][33];
    const int z = blockIdx.z;
    const int widx = z >> 2, s = z & 3;
    const float* src = (widx == 0) ? Wg1 : ((widx == 1) ? Wdr : Wdi);
    const float* sp = src + (size_t)s*DIN*D_;
    unsigned short* dp = dst + (size_t)s*768*DIN + (size_t)widx*D_*DIN;
    const int k0 = blockIdx.x*32, n0 = blockIdx.y*32;
    const int c = threadIdx.x & 31, r0 = threadIdx.x >> 5;
    #pragma unroll
    for (int p = 0; p < 4; ++p)
        t[r0 + p*8][c] = sp[(size_t)(k0 + r0 + p*8)*D_ + n0 + c];
    __syncthreads();
    #pragma unroll
    for (int p = 0; p < 4; ++p)
        dp[(size_t)(n0 + r0 + p*8)*DIN + k0 + c] = f2bf(t[c][r0 + p*8]);
}

// ---------------------------------------------------------------------------
// k1_8p: C[16384][3072] = xb * Bct^T, 256x256 tile, BK=64, 8 waves (2M x 4N),
// 8-phase schedule, counted vmcnt (never 0 in steady state), st-swizzled LDS.
// LDS: 8 half-tile slots of 16 KiB: [buf][op][half] (128 rows x 64 k bf16).
// Phase-local fragment reads (12 ds_read_b128/phase): R2's persistent-frag
// variant regressed (134 vs 125 us) — reads must stay phase-local so they
// issue immediately after the prior barrier and drain during barrier wait.
// Issue schedule: P1:A1[t+1] P2:B0[t+1] P3:A0[t+2] P4:B1[t+2]
//                 P5:A1[t+2] P6:B0[t+2] P7:A0[t+3] P8:B1[t+3]
// Waits: vmcnt(4) at P4 and P8, vmcnt(0) in the last iteration.
// ---------------------------------------------------------------------------
template<bool DRVB>
__global__ __launch_bounds__(512, 2) void k1_8p(
    const unsigned short* __restrict__ xb,
    const unsigned short* __restrict__ Bct,
    const float* __restrict__ bg1, const float* __restrict__ bdr,
    const float* __restrict__ bdi,
    unsigned short* __restrict__ g1b,
    unsigned short* __restrict__ drvb, float* __restrict__ drvf)
{
    __shared__ unsigned short L[8*8192];   // 128 KiB

    const int tid  = threadIdx.x;
    const int wave = tid >> 6, lane = tid & 63;
    const int wmr  = wave >> 2;            // 0..1  (64-row group within a half)
    const int wnr  = wave & 3;             // 0..3  (32-col group within a half)
    const int row0 = blockIdx.x * 256, col0 = blockIdx.y * 256;
    const int cn = lane & 15, quad = lane >> 4;
    const int e8 = cn & 7;
    const int srow = lane >> 3;                    // staging row-in-8
    const int lksw = ((lane & 7) ^ srow) * 8;      // pre-swizzled src k offset

    const unsigned short* Ag = xb  + (size_t)row0 * DIN;
    const unsigned short* Bg = Bct + (size_t)col0 * DIN;

    f32x4 acc[8][4];
    const f32x4 z = {0.f, 0.f, 0.f, 0.f};
    #pragma unroll
    for (int i = 0; i < 8; ++i)
        #pragma unroll
        for (int j = 0; j < 4; ++j) acc[i][j] = z;

#define SLOT(b,o,h) (L + (((b)*4 + (o)*2 + (h)) * 8192))
// stage one 128x64 half-tile (2 x global_load_lds per thread-wave)
#define STAGE(b,o,h,kt,Gp) do { \
    const unsigned short* _g = (Gp) + (size_t)((h)*128 + wave*8 + srow)*DIN \
                             + (size_t)(kt)*64 + lksw; \
    unsigned short* _l = SLOT(b,o,h) + wave*512; \
    GLD_LDS(_g, _l); \
    GLD_LDS(_g + (size_t)64*DIN, _l + 4096); \
} while(0)

#define PHASE(b, ih, jh, STG, WT) do { \
    bf16x8 af[4][2], bfv[2][2]; \
    _Pragma("unroll") \
    for (int ii = 0; ii < 4; ++ii) { \
        const unsigned short* ap = SLOT(b,0,ih) + (size_t)(wmr*64 + ii*16 + cn)*64; \
        _Pragma("unroll") \
        for (int kk = 0; kk < 2; ++kk) \
            af[ii][kk] = *(const bf16x8*)(ap + ((kk*4 + quad) ^ e8)*8); \
    } \
    _Pragma("unroll") \
    for (int jj = 0; jj < 2; ++jj) { \
        const unsigned short* bp = SLOT(b,1,jh) + (size_t)(wnr*32 + jj*16 + cn)*64; \
        _Pragma("unroll") \
        for (int kk = 0; kk < 2; ++kk) \
            bfv[jj][kk] = *(const bf16x8*)(bp + ((kk*4 + quad) ^ e8)*8); \
    } \
    STG; \
    WT; \
    __builtin_amdgcn_s_barrier(); \
    asm volatile("s_waitcnt lgkmcnt(0)" ::: "memory"); \
    __builtin_amdgcn_s_setprio(1); \
    _Pragma("unroll") \
    for (int ii = 0; ii < 4; ++ii) \
        _Pragma("unroll") \
        for (int jj = 0; jj < 2; ++jj) \
            _Pragma("unroll") \
            for (int kk = 0; kk < 2; ++kk) \
                acc[(ih)*4 + ii][(jh)*2 + jj] = \
                    __builtin_amdgcn_mfma_f32_16x16x32_bf16( \
                        af[ii][kk], bfv[jj][kk], \
                        acc[(ih)*4 + ii][(jh)*2 + jj], 0, 0, 0); \
    __builtin_amdgcn_s_setprio(0); \
    __builtin_amdgcn_s_barrier(); \
} while(0)

    // prologue: tile0 (all 4 halves) + tile1 {A0, B1}
    STAGE(0,0,0, 0, Ag); STAGE(0,1,0, 0, Bg);
    STAGE(0,0,1, 0, Ag); STAGE(0,1,1, 0, Bg);
    STAGE(1,0,0, 1, Ag); STAGE(1,1,1, 1, Bg);
    asm volatile("s_waitcnt vmcnt(4)" ::: "memory");
    __builtin_amdgcn_s_barrier();

    #pragma unroll 1
    for (int it = 0; it < 8; ++it) {
        const int t1 = 2*it + 1, t2 = 2*it + 2, t3 = 2*it + 3;
        const bool pf = (it < 7);
        PHASE(0, 0, 0, { STAGE(1,0,1, t1, Ag); }, {});
        PHASE(0, 0, 1, { STAGE(1,1,0, t1, Bg); }, {});
        PHASE(0, 1, 1, { if (pf) STAGE(0,0,0, t2, Ag); }, {});
        PHASE(0, 1, 0, { if (pf) STAGE(0,1,1, t2, Bg); },
              { if (pf) asm volatile("s_waitcnt vmcnt(4)" ::: "memory");
                else    asm volatile("s_waitcnt vmcnt(0)" ::: "memory"); });
        PHASE(1, 0, 0, { if (pf) STAGE(0,0,1, t2, Ag); }, {});
        PHASE(1, 0, 1, { if (pf) STAGE(0,1,0, t2, Bg); }, {});
        PHASE(1, 1, 1, { if (pf) STAGE(1,0,0, t3, Ag); }, {});
        PHASE(1, 1, 0, { if (pf) STAGE(1,1,1, t3, Bg); },
              { if (pf) asm volatile("s_waitcnt vmcnt(4)" ::: "memory");
                else    asm volatile("s_waitcnt vmcnt(0)" ::: "memory"); });
    }
#undef PHASE
#undef STAGE
#undef SLOT

    // epilogue — (s, mat) are block-uniform (768 = 3*256, col0 % 256 == 0)
    const int s    = col0 / 768;
    const int rem  = col0 - s*768;
    const int mat  = rem >> 8;                 // 0:g1  1:dre  2:dim
    const float* bias = (mat == 0) ? bg1 : ((mat == 1) ? bdr : bdi);

    int dloc[4]; float bv[4];
    #pragma unroll
    for (int j = 0; j < 4; ++j) {
        dloc[j] = (j >> 1)*128 + wnr*32 + (j & 1)*16 + cn;
        bv[j] = bias[s*D_ + dloc[j]];
    }

    #pragma unroll
    for (int i = 0; i < 8; ++i) {
        const int m = row0 + (i >> 2)*128 + wmr*64 + (i & 3)*16 + quad*4;
        #pragma unroll
        for (int j = 0; j < 4; ++j) {
            const int d = dloc[j];
            const f32x4 v = acc[i][j];
            if (mat == 0) {
                unsigned short* gp = g1b + ((size_t)s*BT_ + m)*D_ + d;
                #pragma unroll
                for (int r = 0; r < 4; ++r)
                    gp[(size_t)r*D_] = f2bf(fmaxf(v[r] + bv[j], 0.f));
            } else {
                const size_t base = (size_t)m*(S_*2*D_) + s*2*D_
                                  + (mat == 2 ? D_ : 0) + d;
                if (DRVB) {
                    #pragma unroll
                    for (int r = 0; r < 4; ++r)
                        drvb[base + (size_t)r*(S_*2*D_)] = f2bf(v[r] + bv[j]);
                } else {
                    #pragma unroll
                    for (int r = 0; r < 4; ++r)
                        drvf[base + (size_t)r*(S_*2*D_)] = v[r] + bv[j];
                }
            }
        }
    }
}

// ---------------------------------------------------------------------------
// k2: per-s  omg = sigmoid(-(g1 @ Wg2 + bg2)) -> u16 fixed-point
// ---------------------------------------------------------------------------
__global__ __launch_bounds__(256) void k2_mfma(
    const unsigned short* __restrict__ g1b,
    const unsigned short* __restrict__ B2t,
    const float* __restrict__ bg2, unsigned short* __restrict__ omgu)
{
    __shared__ unsigned short As[128*64];
    __shared__ unsigned short Bs[128*64];

    const int tid = threadIdx.x;
    const int wave = tid >> 6, lane = tid & 63;
    const int wm = (wave >> 1) * 64, wn = (wave & 1) * 64;
    const int row0 = blockIdx.x * 128, col0 = blockIdx.y * 128;
    const int s = blockIdx.z;

    const f32x4 z = {0.f, 0.f, 0.f, 0.f};
    f32x4 acc[4][4];
    #pragma unroll
    for (int i = 0; i < 4; ++i)
        #pragma unroll
        for (int j = 0; j < 4; ++j) acc[i][j] = z;

    const unsigned short* Ag = g1b + ((size_t)s*BT_ + row0)*D_;
    const unsigned short* Bg = B2t + (size_t)s*D_*D_ + (size_t)col0*D_;
    const int lrow = lane >> 3;
    const int lksw = ((lane & 7) ^ lrow) * 8;
    const int cn   = lane & 15, quad = lane >> 4;
    const int e    = cn & 7;

    for (int k0 = 0; k0 < D_; k0 += 64) {
        #pragma unroll
        for (int t = 0; t < 4; ++t) {
            const int m0 = wave*32 + t*8;
            GLD_LDS(Ag + (size_t)(m0 + lrow)*D_ + k0 + lksw, As + m0*64);
            GLD_LDS(Bg + (size_t)(m0 + lrow)*D_ + k0 + lksw, Bs + m0*64);
        }
        __syncthreads();
        #pragma unroll
        for (int ks = 0; ks < 2; ++ks) {
            const int offs = (((ks*4 + quad) ^ e)) * 8;
            bf16x8 af[4], bfv[4];
            #pragma unroll
            for (int i = 0; i < 4; ++i)
                af[i] = *(const bf16x8*)(As + (wm + i*16 + cn)*64 + offs);
            #pragma unroll
            for (int j = 0; j < 4; ++j)
                bfv[j] = *(const bf16x8*)(Bs + (wn + j*16 + cn)*64 + offs);
            #pragma unroll
            for (int i = 0; i < 4; ++i)
                #pragma unroll
                for (int j = 0; j < 4; ++j)
                    acc[i][j] = __builtin_amdgcn_mfma_f32_16x16x32_bf16(
                        af[i], bfv[j], acc[i][j], 0, 0, 0);
        }
        __syncthreads();
    }

    const int qr = quad * 4;
    float bv[4];
    #pragma unroll
    for (int j = 0; j < 4; ++j) bv[j] = bg2[s*D_ + col0 + wn + j*16 + cn];

    #pragma unroll
    for (int i = 0; i < 4; ++i) {
        const int m = row0 + wm + i*16 + qr;
        #pragma unroll
        for (int j = 0; j < 4; ++j) {
            const int d = col0 + wn + j*16 + cn;
            const f32x4 v = acc[i][j];
            unsigned short* op = omgu + ((size_t)s*BT_ + m)*D_ + d;
            #pragma unroll
            for (int r = 0; r < 4; ++r) {
                const float om = 1.f / (1.f + __expf(v[r] + bv[j]));
                op[(size_t)r*D_] =
                    (unsigned short)fminf(om * 65536.f, 65535.f);
            }
        }
    }
}

// ---------------------------------------------------------------------------
// k3_fused: single-pass scan (cooperative). 2048 blocks x 128 thr, all
// co-resident (launch_bounds(128,4): <=128 VGPR -> 8 blocks/CU * 256 CU).
// Phase 1: load chunk data into REGISTERS (96 u32/thread), compute summary.
// grid.sync. Phase 2: per-channel Hillis-Steele carry scan (2 ch/block).
// grid.sync. Phase 3: replay from registers with carry, write out.
// Eliminates k3c's 100 MB re-read of omgu+drv.
// ---------------------------------------------------------------------------
template<bool DRVB>
__global__ __launch_bounds__(128, 4) void k3_fused(
    const unsigned short* __restrict__ omgu,
    const unsigned short* __restrict__ drvb, const float* __restrict__ drvf,
    float* __restrict__ out, float4* __restrict__ summ, SC sc)
{
    __shared__ float4 sb[CHUNKS];
    const int blk = blockIdx.x;
    const int c = blk & (CHUNKS-1);
    const int s = (blk >> 7) & (S_-1);
    const int b = blk >> 9;
    const int d2 = threadIdx.x;     // channels 2*d2, 2*d2+1

    const float are = sc.are[s], aim = sc.aim[s], bs = sc.bsc[s];
    const int t0 = c * CL;

    unsigned int cO[CL], cR[CL], cI[CL];   // reg cache (DRVB path)

    // ---- phase 1: load + chunk summary ----
    {
        float Ar[2] = {1.f,1.f}, Ai[2] = {0,0}, Hr[2] = {0,0}, Hi[2] = {0,0};
        #pragma unroll
        for (int t = 0; t < CL; ++t) {
            const int bt = b*T_ + t0 + t;
            const unsigned int ov =
                *(const unsigned int*)(omgu + ((size_t)s*BT_ + bt)*D_ + 2*d2);
            cO[t] = ov;
            const float om[2] = { u16om(ov & 0xFFFFu), u16om(ov >> 16) };
            const size_t base = (size_t)bt*(S_*2*D_) + s*2*D_ + 2*d2;
            float dre[2], dim[2];
            if (DRVB) {
                const unsigned int ur = *(const unsigned int*)(drvb + base);
                const unsigned int ui = *(const unsigned int*)(drvb + base + D_);
                cR[t] = ur; cI[t] = ui;
                dre[0] = bf2f_lo(ur); dre[1] = bf2f_hi(ur);
                dim[0] = bf2f_lo(ui); dim[1] = bf2f_hi(ui);
            } else {
                const float2 fr = *(const float2*)(drvf + base);
                const float2 fi = *(const float2*)(drvf + base + D_);
                dre[0] = fr.x; dre[1] = fr.y; dim[0] = fi.x; dim[1] = fi.y;
            }
            #pragma unroll
            for (int u = 0; u < 2; ++u) {
                const float ar = om[u]*are, ai = om[u]*aim, ob = om[u]*bs;
                const float br = ob*dre[u], bi = ob*dim[u];
                const float nHr = ar*Hr[u] - ai*Hi[u] + br;
                const float nHi = ar*Hi[u] + ai*Hr[u] + bi;
                const float nAr = ar*Ar[u] - ai*Ai[u];
                const float nAi = ar*Ai[u] + ai*Ar[u];
                Hr[u]=nHr; Hi[u]=nHi; Ar[u]=nAr; Ai[u]=nAi;
            }
        }
        const size_t so = ((size_t)(b*S_ + s)*CHUNKS + c)*D_ + 2*d2;
        summ[so]     = make_float4(Ar[0], Ai[0], Hr[0], Hi[0]);
        summ[so + 1] = make_float4(Ar[1], Ai[1], Hr[1], Hi[1]);
    }

    cooperative_groups::this_grid().sync();

    // ---- phase 2: carry scan, 2 channels per block (thread = chunk) ----
    #pragma unroll 1
    for (int ch = 0; ch < 2; ++ch) {
        const int channel = blk*2 + ch;            // 0..4095
        const int dd = channel & (D_-1);
        const int ss = (channel >> 8) & (S_-1);
        const int bb = channel >> 10;
        const size_t off = ((size_t)(bb*S_ + ss)*CHUNKS + d2)*D_ + dd;
        float4 v = summ[off];
        sb[d2] = v;
        __syncthreads();
        #pragma unroll 1
        for (int st = 1; st < CHUNKS; st <<= 1) {
            float4 l;
            if (d2 >= st) l = sb[d2 - st];
            __syncthreads();
            if (d2 >= st) {
                float4 nv;
                nv.x = l.x*v.x - l.y*v.y;          // A = A_l * A_r (complex)
                nv.y = l.x*v.y + l.y*v.x;
                nv.z = v.x*l.z - v.y*l.w + v.z;    // H = A_r*H_l + H_r
                nv.w = v.x*l.w + v.y*l.z + v.w;
                v = nv;
                sb[d2] = v;
            }
            __syncthreads();
        }
        float2 carry = make_float2(0.f, 0.f);      // exclusive: prefix of c-1
        if (d2 > 0) { const float4 p = sb[d2-1]; carry = make_float2(p.z, p.w); }
        *(float2*)&summ[off] = carry;
        __syncthreads();
    }

    cooperative_groups::this_grid().sync();

    // ---- phase 3: replay from registers with carry, write out ----
    {
        const size_t so = ((size_t)(b*S_ + s)*CHUNKS + c)*D_ + 2*d2;
        const float2 c0 = *(const float2*)&summ[so];
        const float2 c1 = *(const float2*)&summ[so + 1];
        float Hr[2] = {c0.x, c1.x}, Hi[2] = {c0.y, c1.y};
        #pragma unroll
        for (int t = 0; t < CL; ++t) {
            const int bt = b*T_ + t0 + t;
            const unsigned int ov = cO[t];
            const float om[2] = { u16om(ov & 0xFFFFu), u16om(ov >> 16) };
            const size_t base = (size_t)bt*(S_*2*D_) + s*2*D_ + 2*d2;
            float dre[2], dim[2];
            if (DRVB) {
                dre[0] = bf2f_lo(cR[t]); dre[1] = bf2f_hi(cR[t]);
                dim[0] = bf2f_lo(cI[t]); dim[1] = bf2f_hi(cI[t]);
            } else {
                const float2 fr = *(const float2*)(drvf + base);
                const float2 fi = *(const float2*)(drvf + base + D_);
                dre[0] = fr.x; dre[1] = fr.y; dim[0] = fi.x; dim[1] = fi.y;
            }
            #pragma unroll
            for (int u = 0; u < 2; ++u) {
                const float ar = om[u]*are, ai = om[u]*aim, ob = om[u]*bs;
                const float br = ob*dre[u], bi = ob*dim[u];
                const float nHr = ar*Hr[u] - ai*Hi[u] + br;
                const float nHi = ar*Hi[u] + ai*Hr[u] + bi;
                Hr[u]=nHr; Hi[u]=nHi;
            }
            *(float2*)(out + base)      = make_float2(Hr[0], Hr[1]);
            *(float2*)(out + base + D_) = make_float2(Hi[0], Hi[1]);
        }
    }
}

// ---------------------------------------------------------------------------
// Fallback 3-kernel scan path (used if cooperative capacity insufficient)
// ---------------------------------------------------------------------------
template<bool DRVB>
__global__ __launch_bounds__(128) void k3a_chunk(
    const unsigned short* __restrict__ omgu,
    const unsigned short* __restrict__ drvb, const float* __restrict__ drvf,
    float4* __restrict__ summ, SC sc)
{
    const int blk = blockIdx.x;
    const int c = blk & (CHUNKS-1);
    const int s = (blk >> 7) & (S_-1);
    const int b = blk >> 9;
    const int d2 = threadIdx.x;

    const float are = sc.are[s], aim = sc.aim[s], bs = sc.bsc[s];
    float Ar[2] = {1.f,1.f}, Ai[2] = {0,0}, Hr[2] = {0,0}, Hi[2] = {0,0};
    const int t0 = c * CL;

    #pragma unroll 4
    for (int t = 0; t < CL; ++t) {
        const int bt = b*T_ + t0 + t;
        const unsigned int ov =
            *(const unsigned int*)(omgu + ((size_t)s*BT_ + bt)*D_ + 2*d2);
        const float om[2] = { u16om(ov & 0xFFFFu), u16om(ov >> 16) };
        const size_t base = (size_t)bt*(S_*2*D_) + s*2*D_ + 2*d2;
        float dre[2], dim[2];
        if (DRVB) {
            const unsigned int ur = *(const unsigned int*)(drvb + base);
            const unsigned int ui = *(const unsigned int*)(drvb + base + D_);
            dre[0] = bf2f_lo(ur); dre[1] = bf2f_hi(ur);
            dim[0] = bf2f_lo(ui); dim[1] = bf2f_hi(ui);
        } else {
            const float2 fr = *(const float2*)(drvf + base);
            const float2 fi = *(const float2*)(drvf + base + D_);
            dre[0] = fr.x; dre[1] = fr.y; dim[0] = fi.x; dim[1] = fi.y;
        }
        #pragma unroll
        for (int u = 0; u < 2; ++u) {
            const float ar = om[u]*are, ai = om[u]*aim, ob = om[u]*bs;
            const float br = ob*dre[u], bi = ob*dim[u];
            const float nHr = ar*Hr[u] - ai*Hi[u] + br;
            const float nHi = ar*Hi[u] + ai*Hr[u] + bi;
            const float nAr = ar*Ar[u] - ai*Ai[u];
            const float nAi = ar*Ai[u] + ai*Ar[u];
            Hr[u]=nHr; Hi[u]=nHi; Ar[u]=nAr; Ai[u]=nAi;
        }
    }
    const size_t so = ((size_t)(b*S_ + s)*CHUNKS + c)*D_ + 2*d2;
    summ[so]     = make_float4(Ar[0], Ai[0], Hr[0], Hi[0]);
    summ[so + 1] = make_float4(Ar[1], Ai[1], Hr[1], Hi[1]);
}

__global__ __launch_bounds__(256) void k3b_scan(float4* __restrict__ summ)
{
    __shared__ float4 sb[2][CHUNKS];
    const int ch = threadIdx.x >> 7;
    const int c  = threadIdx.x & (CHUNKS-1);
    const int channel = blockIdx.x*2 + ch;
    const int d = channel & (D_-1);
    const int s = (channel >> 8) & (S_-1);
    const int b = channel >> 10;
    const size_t off = ((size_t)(b*S_ + s)*CHUNKS + c)*D_ + d;

    float4 v = summ[off];
    sb[ch][c] = v;
    __syncthreads();
    #pragma unroll
    for (int st = 1; st < CHUNKS; st <<= 1) {
        float4 l;
        if (c >= st) l = sb[ch][c - st];
        __syncthreads();
        if (c >= st) {
            float4 nv;
            nv.x = l.x*v.x - l.y*v.y;
            nv.y = l.x*v.y + l.y*v.x;
            nv.z = v.x*l.z - v.y*l.w + v.z;
            nv.w = v.x*l.w + v.y*l.z + v.w;
            v = nv;
            sb[ch][c] = v;
        }
        __syncthreads();
    }
    float2 carry = make_float2(0.f, 0.f);
    if (c > 0) { const float4 p = sb[ch][c-1]; carry = make_float2(p.z, p.w); }
    *(float2*)&summ[off] = carry;
}

template<bool DRVB>
__global__ __launch_bounds__(128) void k3c_final(
    const unsigned short* __restrict__ omgu,
    const unsigned short* __restrict__ drvb, const float* __restrict__ drvf,
    float* __restrict__ out, const float4* __restrict__ summ, SC sc)
{
    const int blk = blockIdx.x;
    const int c = blk & (CHUNKS-1);
    const int s = (blk >> 7) & (S_-1);
    const int b = blk >> 9;
    const int d2 = threadIdx.x;

    const float are = sc.are[s], aim = sc.aim[s], bs = sc.bsc[s];
    const size_t so = ((size_t)(b*S_ + s)*CHUNKS + c)*D_ + 2*d2;
    const float4 v0 = summ[so];
    const float4 v1 = summ[so + 1];
    float Hr[2] = {v0.x, v1.x}, Hi[2] = {v0.y, v1.y};
    const int t0 = c * CL;

    #pragma unroll 4
    for (int t = 0; t < CL; ++t) {
        const int bt = b*T_ + t0 + t;
        const unsigned int ov =
            *(const unsigned int*)(omgu + ((size_t)s*BT_ + bt)*D_ + 2*d2);
        const float om[2] = { u16om(ov & 0xFFFFu), u16om(ov >> 16) };
        const size_t base = (size_t)bt*(S_*2*D_) + s*2*D_ + 2*d2;
        float dre[2], dim[2];
        if (DRVB) {
            const unsigned int ur = *(const unsigned int*)(drvb + base);
            const unsigned int ui = *(const unsigned int*)(drvb + base + D_);
            dre[0] = bf2f_lo(ur); dre[1] = bf2f_hi(ur);
            dim[0] = bf2f_lo(ui); dim[1] = bf2f_hi(ui);
        } else {
            const float2 fr = *(const float2*)(drvf + base);
            const float2 fi = *(const float2*)(drvf + base + D_);
            dre[0] = fr.x; dre[1] = fr.y; dim[0] = fi.x; dim[1] = fi.y;
        }
        #pragma unroll
        for (int u = 0; u < 2; ++u) {
            const float ar = om[u]*are, ai = om[u]*aim, ob = om[u]*bs;
            const float br = ob*dre[u], bi = ob*dim[u];
            const float nHr = ar*Hr[u] - ai*Hi[u] + br;
            const float nHi = ar*Hi[u] + ai*Hr[u] + bi;
            Hr[u]=nHr; Hi[u]=nHi;
        }
        *(float2*)(out + base)      = make_float2(Hr[0], Hr[1]);
        *(float2*)(out + base + D_) = make_float2(Hi[0], Hi[1]);
    }
}

// ---------------------------------------------------------------------------
extern "C" void kernel_launch(void* const* d_in, const int* in_sizes, int n_in,
                              void* d_out, int out_size, void* d_ws, size_t ws_size,
                              hipStream_t stream)
{
    const float* x   = (const float*)d_in[0];
    const float* Wg1 = (const float*)d_in[1];
    const float* bg1 = (const float*)d_in[2];
    const float* Wg2 = (const float*)d_in[3];
    const float* bg2 = (const float*)d_in[4];
    const float* Wdr = (const float*)d_in[5];
    const float* bdr = (const float*)d_in[6];
    const float* Wdi = (const float*)d_in[7];
    const float* bdi = (const float*)d_in[8];
    float* out = (float*)d_out;

    // workspace layout (141.0 MB total):
    //   [0, 33.5M)      g1b (k1..k2)  -> summ (k3)              alias OK
    //   [33.5M, 34.1M)  B2t (conv..k2)
    //   [34.1M, 67.6M)  xb  (conv..k1) -> omgu (k2..k3)         alias OK
    //   [67.6M, 73.9M)  Bct (conv..k1)
    //   [73.9M, 141.0M) drvb bf16 (k1..k3)   [if ws fits, else fp32 in out]
    char* ws = (char*)d_ws;
    unsigned short* g1b  = (unsigned short*)(ws + 0);
    float4*         summ = (float4*)(ws + 0);
    unsigned short* B2t  = (unsigned short*)(ws + 33554432);
    unsigned short* xb   = (unsigned short*)(ws + 34078720);
    unsigned short* omgu = (unsigned short*)(ws + 34078720);
    unsigned short* Bct  = (unsigned short*)(ws + 67633152);
    unsigned short* drvb = (unsigned short*)(ws + 73924608);
    const bool drv_bf16 = ws_size >= (size_t)73924608 + 67108864;

    SC sc;
    {
        const double r[S_]  = {1.0, 0.999, 0.9495, 0.9};
        const double th[S_] = {0.0, 0.01, 0.505, 1.0};
        for (int s = 0; s < S_; ++s) {
            sc.are[s] = (float)(r[s] * cos(th[s]));
            sc.aim[s] = (float)(r[s] * sin(th[s]));
            sc.bsc[s] = (r[s] >= 1.0) ? (float)(1.0/16.0) : (float)(1.0 - r[s]);
        }
    }

    // conversions
    kconv_x<<<(BT_*DIN)/1024, 256, 0, stream>>>(x, xb);
    kconv_w3<<<dim3(32,8,12), 256, 0, stream>>>(Wg1, Wdr, Wdi, Bct);
    kconv_w<<<dim3(8,8,S_),  256, 0, stream>>>(Wg2, B2t, D_, D_, (size_t)D_*D_);

    // GEMMs
    if (drv_bf16)
        k1_8p<true><<<dim3(BT_/256, GN/256), 512, 0, stream>>>(
            xb, Bct, bg1, bdr, bdi, g1b, drvb, out);
    else
        k1_8p<false><<<dim3(BT_/256, GN/256), 512, 0, stream>>>(
            xb, Bct, bg1, bdr, bdi, g1b, drvb, out);
    k2_mfma<<<dim3(BT_/128, D_/128, S_), 256, 0, stream>>>(g1b, B2t, bg2, omgu);

    // scan: prefer single-pass cooperative kernel; fall back to 3 kernels.
    int coopOk = 0;
    {
        int nb = 0;
        hipError_t e = hipOccupancyMaxActiveBlocksPerMultiprocessor(
            &nb,
            drv_bf16 ? reinterpret_cast<const void*>(&k3_fused<true>)
                     : reinterpret_cast<const void*>(&k3_fused<false>),
            128, 0);
        if (e == hipSuccess && nb >= 8) coopOk = 1;
    }

    if (coopOk) {
        const unsigned short* a_omgu = omgu;
        const unsigned short* a_drvb = drvb;
        const float* a_drvf = out;
        float* a_out = out;
        float4* a_summ = summ;
        void* args[6] = { (void*)&a_omgu, (void*)&a_drvb, (void*)&a_drvf,
                          (void*)&a_out, (void*)&a_summ, (void*)&sc };
        hipError_t e = hipLaunchCooperativeKernel(
            drv_bf16 ? reinterpret_cast<const void*>(&k3_fused<true>)
                     : reinterpret_cast<const void*>(&k3_fused<false>),
            dim3(B_*S_*CHUNKS), dim3(128), args, 0, stream);
        if (e != hipSuccess) coopOk = 0;   // fall through to 3-kernel path
    }
    if (!coopOk) {
        if (drv_bf16) {
            k3a_chunk<true><<<B_*S_*CHUNKS, 128, 0, stream>>>(omgu, drvb, out, summ, sc);
            k3b_scan       <<<(B_*S_*D_)/2, 256, 0, stream>>>(summ);
            k3c_final<true><<<B_*S_*CHUNKS, 128, 0, stream>>>(omgu, drvb, out, out, summ, sc);
        } else {
            k3a_chunk<false><<<B_*S_*CHUNKS, 128, 0, stream>>>(omgu, drvb, out, summ, sc);
            k3b_scan        <<<(B_*S_*D_)/2, 256, 0, stream>>>(summ);
            k3c_final<false><<<B_*S_*CHUNKS, 128, 0, stream>>>(omgu, drvb, out, out, summ, sc);
        }
    }
}